// Round 17
// baseline (69.683 us; speedup 1.0000x reference)
//
#include <hip/hip_runtime.h>
#include <math.h>

#define NN 100000
#define EE 1600000
#define HH 128
#define RR 500
#define AA 16
#define LN_EPS 1e-5f

// Bucketing: nodes -> 391 buckets of 256; payload packs (src<<8 | dst&255) in u32.
#define BSH 8
#define NPB 256
#define NB 391                   // ceil(100000/256)
#define MAXPB 4608               // mean 4096, +8 sigma
#define EPW 8192                 // edges per scatter workgroup
#define SCT 512                  // scatter threads
#define NWG_SC ((EE + EPW - 1) / EPW)   // 196
#define NZW 16                   // zpart slices (32 k-rows each, covers 500)
#define NSREP 8                  // S/T2 replicas
#define NTW 16                   // tail1 WGs

// WG0: zero gctr/S8/T2_8. WGs 1..16: zpart slices.
__global__ __launch_bounds__(256) void k_init_esn(unsigned int* __restrict__ zero_region,
                                                  const float* __restrict__ esn,
                                                  const float* __restrict__ fc1_w,
                                                  float* __restrict__ zpart) {
    const int w = blockIdx.x, t = threadIdx.x;
    if (w == 0) {
        for (int j = t; j < 1544; j += 256) zero_region[j] = 0u;   // gctr|S8|T2_8
        return;
    }
    const int sl = w - 1;
    const int k0 = sl * 32;
    const int k1 = min(k0 + 32, RR);
    if (t < HH) {
        float acc = 0.f;
        for (int k = k0; k < k1; ++k)
            acc = fmaf(esn[k], fc1_w[(size_t)(HH + k) * HH + t], acc);
        zpart[(size_t)sl * HH + t] = acc;
    }
}

// Bucket edges by dst — single LDS-atomic pass (rank yields slot AND count).
__global__ __launch_bounds__(SCT) void k_scatter(const int* __restrict__ src,
                                                 const int* __restrict__ dst,
                                                 unsigned int* __restrict__ gctr,
                                                 unsigned int* __restrict__ payload) {
    __shared__ unsigned int rank[512], hbase[512];
    const int t = threadIdx.x;
    rank[t] = 0u; hbase[t] = 0u;
    __syncthreads();
    const int e0 = blockIdx.x * EPW;
    const int ecnt = max(0, min(EPW, EE - e0));   // mult of 4
    const int nv = ecnt >> 2;
    const int4* d4 = reinterpret_cast<const int4*>(dst + e0);
    const int4* s4 = reinterpret_cast<const int4*>(src + e0);

    unsigned int pw[16], pbr[16];
    bool vk[4];

    #pragma unroll
    for (int kk = 0; kk < 4; ++kk) {
        const int k = t + kk * SCT;
        vk[kk] = (k < nv);
        if (vk[kk]) {
            int4 d = d4[k];
            int4 s = s4[k];
            #define GRAB(i, SS, DD) { \
                unsigned int dd = (unsigned)(DD), ss = (unsigned)(SS); \
                unsigned int b = dd >> BSH; \
                unsigned int r = atomicAdd(&rank[b], 1u); \
                pw[kk * 4 + i]  = (ss << BSH) | (dd & (NPB - 1)); \
                pbr[kk * 4 + i] = (b << 16) | (r & 0xFFFFu); }
            GRAB(0, s.x, d.x) GRAB(1, s.y, d.y) GRAB(2, s.z, d.z) GRAB(3, s.w, d.w)
            #undef GRAB
        }
    }
    __syncthreads();

    if (t < NB && rank[t] > 0u) hbase[t] = atomicAdd(&gctr[t], rank[t]);
    __syncthreads();

    #pragma unroll
    for (int kk = 0; kk < 4; ++kk) {
        if (vk[kk]) {
            #define PUT(i) { \
                unsigned int b = pbr[kk * 4 + i] >> 16; \
                unsigned int slot = hbase[b] + (pbr[kk * 4 + i] & 0xFFFFu); \
                if (slot < MAXPB) payload[(size_t)b * MAXPB + slot] = pw[kk * 4 + i]; }
            PUT(0) PUT(1) PUT(2) PUT(3)
            #undef PUT
        }
    }
}

// Per bucket, 1024 threads: rank each edge within its dst (1 LDS atomic/edge),
// 256-scan -> dst-sorted src list payload2 + packed sstart (start<<16|len),
// plus rsv = rsqrt(deg), g = rsv*f. Sets up ATOMIC-FREE aggregation in k_bagg.
__global__ __launch_bounds__(1024) void k_bdeg_g(const unsigned int* __restrict__ gctr,
        const unsigned int* __restrict__ payload,
        const float* __restrict__ nf,
        float* __restrict__ rsv, float* __restrict__ g,
        unsigned int* __restrict__ payload2, unsigned int* __restrict__ sstart) {
    __shared__ unsigned int hist[NPB];
    __shared__ unsigned int start[NPB];
    const int b = blockIdx.x, t = threadIdx.x;
    if (t < NPB) hist[t] = 0u;
    __syncthreads();
    const unsigned int cnt = min(gctr[b], (unsigned int)MAXPB);
    const unsigned int* pl = payload + (size_t)b * MAXPB;
    const uint4* pl4 = reinterpret_cast<const uint4*>(pl);
    const unsigned int nv = cnt >> 2;

    uint4 pv0, pv1;
    unsigned int rk0[4], rk1[4];
    const bool v0 = (unsigned)t < nv;
    const bool v1 = (unsigned)(t + 1024) < nv;   // nv <= 1152
    if (v0) {
        pv0 = pl4[t];
        rk0[0] = atomicAdd(&hist[pv0.x & (NPB - 1)], 1u);
        rk0[1] = atomicAdd(&hist[pv0.y & (NPB - 1)], 1u);
        rk0[2] = atomicAdd(&hist[pv0.z & (NPB - 1)], 1u);
        rk0[3] = atomicAdd(&hist[pv0.w & (NPB - 1)], 1u);
    }
    if (v1) {
        pv1 = pl4[t + 1024];
        rk1[0] = atomicAdd(&hist[pv1.x & (NPB - 1)], 1u);
        rk1[1] = atomicAdd(&hist[pv1.y & (NPB - 1)], 1u);
        rk1[2] = atomicAdd(&hist[pv1.z & (NPB - 1)], 1u);
        rk1[3] = atomicAdd(&hist[pv1.w & (NPB - 1)], 1u);
    }
    unsigned int tp = 0u, tr = 0u;
    const bool vt = (unsigned)t < (cnt & 3u);
    if (vt) {
        tp = pl[(nv << 2) + t];
        tr = atomicAdd(&hist[tp & (NPB - 1)], 1u);
    }
    __syncthreads();

    // exclusive scan of hist -> start (Hillis-Steele, barriers unconditional)
    if (t < NPB) start[t] = hist[t];
    __syncthreads();
    for (int off = 1; off < NPB; off <<= 1) {
        unsigned int v = 0u;
        if (t < NPB && t >= off) v = start[t - off];
        __syncthreads();
        if (t < NPB) start[t] += v;
        __syncthreads();
    }
    if (t < NPB) start[t] -= hist[t];      // exclusive prefix
    __syncthreads();

    // scatter srcs into dst-sorted order
    unsigned int* p2 = payload2 + (size_t)b * MAXPB;
    if (v0) {
        p2[start[pv0.x & (NPB - 1)] + rk0[0]] = pv0.x >> BSH;
        p2[start[pv0.y & (NPB - 1)] + rk0[1]] = pv0.y >> BSH;
        p2[start[pv0.z & (NPB - 1)] + rk0[2]] = pv0.z >> BSH;
        p2[start[pv0.w & (NPB - 1)] + rk0[3]] = pv0.w >> BSH;
    }
    if (v1) {
        p2[start[pv1.x & (NPB - 1)] + rk1[0]] = pv1.x >> BSH;
        p2[start[pv1.y & (NPB - 1)] + rk1[1]] = pv1.y >> BSH;
        p2[start[pv1.z & (NPB - 1)] + rk1[2]] = pv1.z >> BSH;
        p2[start[pv1.w & (NPB - 1)] + rk1[3]] = pv1.w >> BSH;
    }
    if (vt) p2[start[tp & (NPB - 1)] + tr] = tp >> BSH;

    if (t < NPB) {
        sstart[(size_t)b * NPB + t] = (start[t] << 16) | (hist[t] & 0xFFFFu);
        int node = (b << BSH) + t;
        if (node < NN) {
            float df = 1.0f + (float)hist[t];
            float rs = rsqrtf(df);
            rsv[node] = rs;
            float2 f = *reinterpret_cast<const float2*>(&nf[2 * node]);
            float2 gv; gv.x = rs * f.x; gv.y = rs * f.y;
            *reinterpret_cast<float2*>(&g[2 * node]) = gv;
        }
    }
}

// Per bucket, 256 threads, ONE THREAD PER DST: serial register-sum of the
// dst-sorted src run (ZERO LDS atomics), plain LDS stores, fold self-loop,
// GCN channel pass + relu; S/T2 into 8 spread replicas.
__global__ __launch_bounds__(256) void k_bagg_node(const unsigned int* __restrict__ payload2,
        const unsigned int* __restrict__ sstart,
        const float* __restrict__ g, const float* __restrict__ rsv,
        const float* __restrict__ gcn_w, const float* __restrict__ gcn_b,
        float* __restrict__ S8, float* __restrict__ T2_8) {
    __shared__ float agg[NPB * 2];
    __shared__ float shSf[HH];
    __shared__ float shw[4];
    const int b = blockIdx.x, t = threadIdx.x;
    if (t < HH) shSf[t] = 0.f;

    const int nvalid = min(NPB, NN - (b << BSH));
    const unsigned int* p2 = payload2 + (size_t)b * MAXPB;

    float ax = 0.f, ay = 0.f;
    if (t < nvalid) {
        unsigned int sl = sstart[(size_t)b * NPB + t];
        unsigned int s0 = sl >> 16, len = sl & 0xFFFFu;
        #pragma unroll 4
        for (unsigned int k = 0; k < len; ++k) {
            unsigned int s = p2[s0 + k];
            float2 gv = *reinterpret_cast<const float2*>(&g[2 * s]);
            ax += gv.x; ay += gv.y;
        }
        int node = (b << BSH) + t;
        float rs = rsv[node];
        float2 gv = *reinterpret_cast<const float2*>(&g[2 * node]);
        agg[t]       = rs * (ax + gv.x);
        agg[NPB + t] = rs * (ay + gv.y);
    } else {
        agg[t]       = 0.f;
        agg[NPB + t] = 0.f;
    }
    __syncthreads();

    const int ch = t & (HH - 1), slot = t >> 7;   // slot 0..1
    const float w0 = gcn_w[ch], w1 = gcn_w[HH + ch], bb = gcn_b[ch];
    float accS = 0.f, accT2 = 0.f;
    for (int j = slot; j < nvalid; j += 2) {
        float x = fmaf(agg[j], w0, fmaf(agg[NPB + j], w1, bb));
        float r = fmaxf(x, 0.f);
        accS  += r;
        accT2 += r * r;
    }
    atomicAdd(&shSf[ch], accS);
    float v = accT2;
    for (int o = 32; o; o >>= 1) v += __shfl_down(v, o, 64);
    if ((t & 63) == 0) shw[t >> 6] = v;
    __syncthreads();
    const int rep = b & (NSREP - 1);
    if (t < HH) atomicAdd(&S8[rep * HH + t], shSf[t]);
    if (t == 0) {
        float s2 = 0.f;
        #pragma unroll
        for (int w = 0; w < 4; ++w) s2 += shw[w];
        atomicAdd(&T2_8[rep], s2);
    }
}

// 16 WGs x 128 threads: partial W1^T products over fc1_w[0:128] k-rows.
__global__ __launch_bounds__(128) void k_tail1(const float* __restrict__ S8,
                                               const float* __restrict__ ln_w,
                                               const float* __restrict__ ln_b,
                                               const float* __restrict__ fc1_w,
                                               float* __restrict__ upart,
                                               float* __restrict__ c1part,
                                               float* __restrict__ c2part) {
    const int i = blockIdx.x, t = threadIdx.x;
    __shared__ float sh_sw[8], sh_lw[8], sh_lb[8];
    if (t < 8) {
        const int k = i * 8 + t;
        float s = 0.f;
        #pragma unroll
        for (int r = 0; r < NSREP; ++r) s += S8[r * HH + k];
        float lw = ln_w[k];
        sh_sw[t] = lw * s;
        sh_lw[t] = lw;
        sh_lb[t] = ln_b[k];
    }
    __syncthreads();
    float u = 0.f, c1 = 0.f, c2 = 0.f;
    #pragma unroll
    for (int kk = 0; kk < 8; ++kk) {
        float w = fc1_w[(size_t)(i * 8 + kk) * HH + t];
        u  = fmaf(sh_sw[kk], w, u);
        c1 = fmaf(sh_lw[kk], w, c1);
        c2 = fmaf(sh_lb[kk], w, c2);
    }
    upart[(size_t)i * HH + t]  = u;
    c1part[(size_t)i * HH + t] = c1;
    c2part[(size_t)i * HH + t] = c2;
}

// 1 WG x 128 threads: LN constants, combine partials, fc2, log_softmax.
__global__ __launch_bounds__(128) void k_tail2(const float* __restrict__ S8,
                                               const float* __restrict__ T2_8,
                                               const float* __restrict__ upart,
                                               const float* __restrict__ c1part,
                                               const float* __restrict__ c2part,
                                               const float* __restrict__ zpart,
                                               const float* __restrict__ fc1_b,
                                               const float* __restrict__ fc2_w,
                                               const float* __restrict__ fc2_b,
                                               float* __restrict__ out) {
    const int t = threadIdx.x;
    __shared__ float sh_z[HH], sh_logits[AA], shred[2], sh_t2[8];

    float s = 0.f;
    #pragma unroll
    for (int r = 0; r < NSREP; ++r) s += S8[r * HH + t];
    float vv = s;
    for (int o = 32; o; o >>= 1) vv += __shfl_down(vv, o, 64);
    if ((t & 63) == 0) shred[t >> 6] = vv;
    if (t < 8) sh_t2[t] = T2_8[t];
    __syncthreads();

    const float T1 = shred[0] + shred[1];
    float T2v = 0.f;
    #pragma unroll
    for (int r = 0; r < 8; ++r) T2v += sh_t2[r];
    const float cntf = (float)NN * (float)HH;
    const float mean = T1 / cntf;
    const float var  = T2v / cntf - mean * mean;
    const float denom = sqrtf(var) + LN_EPS;
    const float inv_denom = 1.0f / denom;
    const float nmean = (float)NN * mean;

    float u = 0.f, c1 = 0.f, c2 = 0.f, zs = 0.f;
    #pragma unroll
    for (int i = 0; i < NTW; ++i) {
        u  += upart[(size_t)i * HH + t];
        c1 += c1part[(size_t)i * HH + t];
        c2 += c2part[(size_t)i * HH + t];
        zs += zpart[(size_t)i * HH + t];
    }
    float fc1p = (u - nmean * c1) * inv_denom + (float)NN * c2;
    sh_z[t] = fmaxf(fc1p + zs + fc1_b[t], 0.f);
    __syncthreads();

    if (t < AA) {
        float l = fc2_b[t];
        for (int j = 0; j < HH; ++j)
            l = fmaf(sh_z[j], fc2_w[j * AA + t], l);
        sh_logits[t] = l;
    }
    __syncthreads();

    if (t == 0) {
        float m = sh_logits[0];
        for (int a = 1; a < AA; ++a) m = fmaxf(m, sh_logits[a]);
        float sum = 0.f;
        for (int a = 0; a < AA; ++a) sum += expf(sh_logits[a] - m);
        float lse = m + logf(sum);
        for (int a = 0; a < AA; ++a) out[a] = sh_logits[a] - lse;
    }
}

// ---------------- fallback path (round-2 known-good) ----------------

__global__ void k_initf(unsigned int* __restrict__ p, int n) {
    int i = blockIdx.x * blockDim.x + threadIdx.x;
    int stride = gridDim.x * blockDim.x;
    for (int j = i; j < n; j += stride) p[j] = 0u;
}

__global__ void k_deg1(const int* __restrict__ dst, int* __restrict__ deg, int e) {
    int i = blockIdx.x * blockDim.x + threadIdx.x;
    if (i < e) atomicAdd(&deg[dst[i]], 1);
}

__global__ void k_g1(const int* __restrict__ deg, const float* __restrict__ nf,
                     float* __restrict__ degf, float* __restrict__ g, int n) {
    int i = blockIdx.x * blockDim.x + threadIdx.x;
    if (i < n) {
        float df = (float)(1 + deg[i]);
        degf[i] = df;
        float rs = rsqrtf(df);
        float2 f = *reinterpret_cast<const float2*>(&nf[2 * i]);
        float2 gv; gv.x = rs * f.x; gv.y = rs * f.y;
        *reinterpret_cast<float2*>(&g[2 * i]) = gv;
    }
}

__global__ void k_edge1(const int* __restrict__ src, const int* __restrict__ dst,
                        const float* __restrict__ g, float* __restrict__ B, int e) {
    int i = blockIdx.x * blockDim.x + threadIdx.x;
    if (i < e) {
        int s = src[i], d = dst[i];
        float2 gv = *reinterpret_cast<const float2*>(&g[2 * s]);
        atomicAdd(&B[2 * d],     gv.x);
        atomicAdd(&B[2 * d + 1], gv.y);
    }
}

__global__ void k_node(const float* __restrict__ nf, const float* __restrict__ degf,
                       const float* __restrict__ B,
                       const float* __restrict__ gcn_w, const float* __restrict__ gcn_b,
                       float* __restrict__ S, float* __restrict__ T2, int n) {
    const int ch   = threadIdx.x & (HH - 1);
    const int slot = threadIdx.x >> 7;
    const float w0 = gcn_w[ch];
    const float w1 = gcn_w[HH + ch];
    const float b  = gcn_b[ch];
    float accS = 0.f, accT2 = 0.f;
    for (int i = blockIdx.x * 2 + slot; i < n; i += gridDim.x * 2) {
        float df   = degf[i];
        float invd = 1.0f / df;
        float rs   = rsqrtf(df);
        float2 bv = *reinterpret_cast<const float2*>(&B[2 * i]);
        float2 f  = *reinterpret_cast<const float2*>(&nf[2 * i]);
        float b0 = rs * bv.x + f.x * invd;
        float b1 = rs * bv.y + f.y * invd;
        float xv = fmaf(b0, w0, fmaf(b1, w1, b));
        float r  = fmaxf(xv, 0.f);
        accS  += r;
        accT2 += r * r;
    }
    __shared__ float shS[HH];
    if (slot == 1) shS[ch] = accS;
    __syncthreads();
    if (slot == 0) atomicAdd(&S[ch], accS + shS[ch]);
    float v = accT2;
    for (int o = 32; o; o >>= 1) v += __shfl_down(v, o, 64);
    __shared__ float shw[4];
    if ((threadIdx.x & 63) == 0) shw[threadIdx.x >> 6] = v;
    __syncthreads();
    if (threadIdx.x == 0) atomicAdd(T2, shw[0] + shw[1] + shw[2] + shw[3]);
}

__global__ void k_final(const float* __restrict__ S, const float* __restrict__ T2ptr,
                        const float* __restrict__ esn,
                        const float* __restrict__ ln_w, const float* __restrict__ ln_b,
                        const float* __restrict__ fc1_w, const float* __restrict__ fc1_b,
                        const float* __restrict__ fc2_w, const float* __restrict__ fc2_b,
                        float* __restrict__ out) {
    const int t = threadIdx.x;
    __shared__ float sh_pooled[HH];
    __shared__ float sh_z[HH];
    __shared__ float sh_logits[AA];
    __shared__ float shred[2];

    float s = S[t];
    float v = s;
    for (int o = 32; o; o >>= 1) v += __shfl_down(v, o, 64);
    if ((t & 63) == 0) shred[t >> 6] = v;
    __syncthreads();
    const float T1 = shred[0] + shred[1];
    const float T2 = *T2ptr;
    const float cnt = (float)NN * (float)HH;
    const float mean = T1 / cnt;
    const float var  = T2 / cnt - mean * mean;
    const float denom = sqrtf(var) + LN_EPS;
    sh_pooled[t] = ln_w[t] * (s - (float)NN * mean) / denom + (float)NN * ln_b[t];
    __syncthreads();

    float acc = fc1_b[t];
    for (int k = 0; k < HH; ++k)
        acc = fmaf(sh_pooled[k], fc1_w[k * HH + t], acc);
    for (int k = 0; k < RR; ++k)
        acc = fmaf(esn[k], fc1_w[(HH + k) * HH + t], acc);
    sh_z[t] = fmaxf(acc, 0.f);
    __syncthreads();

    if (t < AA) {
        float l = fc2_b[t];
        for (int j = 0; j < HH; ++j)
            l = fmaf(sh_z[j], fc2_w[j * AA + t], l);
        sh_logits[t] = l;
    }
    __syncthreads();

    if (t == 0) {
        float m = sh_logits[0];
        for (int a = 1; a < AA; ++a) m = fmaxf(m, sh_logits[a]);
        float sum = 0.f;
        for (int a = 0; a < AA; ++a) sum += expf(sh_logits[a] - m);
        float lse = m + logf(sum);
        for (int a = 0; a < AA; ++a) out[a] = sh_logits[a] - lse;
    }
}

extern "C" void kernel_launch(void* const* d_in, const int* in_sizes, int n_in,
                              void* d_out, int out_size, void* d_ws, size_t ws_size,
                              hipStream_t stream) {
    const float* nf     = (const float*)d_in[0];
    const int*   ei     = (const int*)d_in[1];
    const float* esn    = (const float*)d_in[2];
    const float* gcn_w  = (const float*)d_in[3];
    const float* gcn_b  = (const float*)d_in[4];
    const float* ln_w   = (const float*)d_in[5];
    const float* ln_b   = (const float*)d_in[6];
    const float* fc1_w  = (const float*)d_in[7];
    const float* fc1_b  = (const float*)d_in[8];
    const float* fc2_w  = (const float*)d_in[9];
    const float* fc2_b  = (const float*)d_in[10];
    float* out = (float*)d_out;
    float* ws  = (float*)d_ws;

    // Layout (word offsets):
    //   gctr:0(512) | S8:512(1024) | T2_8:1536(8) | upart:1544(2048) | c1part:3592(2048)
    //   | c2part:5640(2048) | zpart:7688(2048) | sstart:9736(NB*NPB)
    //   | payload:109832(NB*MAXPB) | payload2:+NB*MAXPB | rsv(NN) | g(2NN)
    const size_t OFF_S8       = 512;
    const size_t OFF_T28      = OFF_S8 + NSREP * HH;            // 1536
    const size_t OFF_UPART    = OFF_T28 + 8;                    // 1544
    const size_t OFF_C1       = OFF_UPART + (size_t)NTW * HH;   // 3592
    const size_t OFF_C2       = OFF_C1 + (size_t)NTW * HH;      // 5640
    const size_t OFF_ZPART    = OFF_C2 + (size_t)NTW * HH;      // 7688
    const size_t OFF_SSTART   = OFF_ZPART + (size_t)NZW * HH;   // 9736
    const size_t OFF_PAYLOAD  = OFF_SSTART + (size_t)NB * NPB;  // 109832 (mult of 4)
    const size_t OFF_PAYLOAD2 = OFF_PAYLOAD + (size_t)NB * MAXPB;
    const size_t OFF_RSV      = OFF_PAYLOAD2 + (size_t)NB * MAXPB;
    const size_t OFF_G        = OFF_RSV + NN;                   // even -> float2 ok
    const size_t NEED_BKT     = (OFF_G + 2 * (size_t)NN) * 4;

    if (ws_size >= NEED_BKT) {
        unsigned int* gctr     = (unsigned int*)ws;
        float*        S8       = ws + OFF_S8;
        float*        T2_8     = ws + OFF_T28;
        float*        upart    = ws + OFF_UPART;
        float*        c1part   = ws + OFF_C1;
        float*        c2part   = ws + OFF_C2;
        float*        zpart    = ws + OFF_ZPART;
        unsigned int* sstart   = (unsigned int*)ws + OFF_SSTART;
        unsigned int* payload  = (unsigned int*)ws + OFF_PAYLOAD;
        unsigned int* payload2 = (unsigned int*)ws + OFF_PAYLOAD2;
        float*        rsv      = ws + OFF_RSV;
        float*        g        = ws + OFF_G;

        hipLaunchKernelGGL(k_init_esn,  dim3(NZW + 1), dim3(256),  0, stream,
                           (unsigned int*)ws, esn, fc1_w, zpart);
        hipLaunchKernelGGL(k_scatter,   dim3(NWG_SC),  dim3(SCT),  0, stream, ei, ei + EE, gctr, payload);
        hipLaunchKernelGGL(k_bdeg_g,    dim3(NB),      dim3(1024), 0, stream,
                           gctr, payload, nf, rsv, g, payload2, sstart);
        hipLaunchKernelGGL(k_bagg_node, dim3(NB),      dim3(256),  0, stream,
                           payload2, sstart, g, rsv, gcn_w, gcn_b, S8, T2_8);
        hipLaunchKernelGGL(k_tail1,     dim3(NTW),     dim3(128),  0, stream,
                           S8, ln_w, ln_b, fc1_w, upart, c1part, c2part);
        hipLaunchKernelGGL(k_tail2,     dim3(1),       dim3(128),  0, stream,
                           S8, T2_8, upart, c1part, c2part, zpart, fc1_b, fc2_w, fc2_b, out);
    } else {
        // Fallback: known-good atomic path.
        int*   deg  = (int*)ws;
        float* B    = ws + NN;
        float* S    = ws + 3 * (size_t)NN;
        float* T2   = ws + 3 * (size_t)NN + 128;
        float* degf = ws + 3 * (size_t)NN + 130;
        float* g    = ws + 4 * (size_t)NN + 130;
        const int eb = (EE + 255) / 256;
        const int nb = (NN + 255) / 256;
        hipLaunchKernelGGL(k_initf, dim3(2048), dim3(256), 0, stream, (unsigned int*)ws, 3 * NN + 129);
        hipLaunchKernelGGL(k_deg1,  dim3(eb),   dim3(256), 0, stream, ei + EE, deg, EE);
        hipLaunchKernelGGL(k_g1,    dim3(nb),   dim3(256), 0, stream, deg, nf, degf, g, NN);
        hipLaunchKernelGGL(k_edge1, dim3(eb),   dim3(256), 0, stream, ei, ei + EE, g, B, EE);
        hipLaunchKernelGGL(k_node,  dim3(512),  dim3(256), 0, stream, nf, degf, B, gcn_w, gcn_b, S, T2, NN);
        hipLaunchKernelGGL(k_final, dim3(1),    dim3(128), 0, stream,
                           S, T2, esn, ln_w, ln_b, fc1_w, fc1_b, fc2_w, fc2_b, out);
    }
}

// Round 18
// 66.119 us; speedup vs baseline: 1.0539x; 1.0539x over previous
//
#include <hip/hip_runtime.h>
#include <math.h>

#define NN 100000
#define EE 1600000
#define HH 128
#define RR 500
#define AA 16
#define LN_EPS 1e-5f

// Bucketing: nodes -> 391 buckets of 256; payload packs (src<<8 | dst&255) in u32.
#define BSH 8
#define NPB 256
#define NB 391                   // ceil(100000/256)
#define MAXPB 4608               // mean 4096, +8 sigma
#define EPW 8192                 // edges per scatter workgroup
#define SCT 1024                 // scatter threads (8 edges/thread; 2x waves vs r15)
#define NWG_SC ((EE + EPW - 1) / EPW)   // 196
#define NZW 64                   // zpart slices (8 k-rows each, covers 500)

// WG0: zero gctr/S/T2/done. WGs 1..64: zpart[w][ch] = sum_k esn[k]*fc1_w[(HH+k)*HH+ch].
__global__ __launch_bounds__(256) void k_init_esn(unsigned int* __restrict__ zero_region,
                                                  const float* __restrict__ esn,
                                                  const float* __restrict__ fc1_w,
                                                  float* __restrict__ zpart) {
    const int w = blockIdx.x, t = threadIdx.x;
    if (w == 0) {
        for (int j = t; j < 642; j += 256) zero_region[j] = 0u;   // gctr|S|T2|done
        return;
    }
    const int sl = w - 1;                 // 0..63
    const int k0 = sl * 8;
    const int k1 = min(k0 + 8, RR);
    if (t < HH) {
        float acc = 0.f;
        for (int k = k0; k < k1; ++k)
            acc = fmaf(esn[k], fc1_w[(size_t)(HH + k) * HH + t], acc);
        zpart[(size_t)sl * HH + t] = acc;
    }
}

// Bucket edges by dst — single LDS-atomic pass (rank yields slot AND count),
// 1024 threads (16 waves) to hide LDS-atomic + scattered-write latency.
__global__ __launch_bounds__(SCT) void k_scatter(const int* __restrict__ src,
                                                 const int* __restrict__ dst,
                                                 unsigned int* __restrict__ gctr,
                                                 unsigned int* __restrict__ payload) {
    __shared__ unsigned int rank[512], hbase[512];
    const int t = threadIdx.x;
    if (t < 512) { rank[t] = 0u; hbase[t] = 0u; }
    __syncthreads();
    const int e0 = blockIdx.x * EPW;
    const int ecnt = max(0, min(EPW, EE - e0));   // mult of 4
    const int nv = ecnt >> 2;                     // <= 2048
    const int4* d4 = reinterpret_cast<const int4*>(dst + e0);
    const int4* s4 = reinterpret_cast<const int4*>(src + e0);

    unsigned int pw[8], pbr[8];
    bool vk[2];

    #pragma unroll
    for (int kk = 0; kk < 2; ++kk) {
        const int k = t + kk * SCT;
        vk[kk] = (k < nv);
        if (vk[kk]) {
            int4 d = d4[k];
            int4 s = s4[k];
            #define GRAB(i, SS, DD) { \
                unsigned int dd = (unsigned)(DD), ss = (unsigned)(SS); \
                unsigned int b = dd >> BSH; \
                unsigned int r = atomicAdd(&rank[b], 1u); \
                pw[kk * 4 + i]  = (ss << BSH) | (dd & (NPB - 1)); \
                pbr[kk * 4 + i] = (b << 16) | (r & 0xFFFFu); }
            GRAB(0, s.x, d.x) GRAB(1, s.y, d.y) GRAB(2, s.z, d.z) GRAB(3, s.w, d.w)
            #undef GRAB
        }
    }
    __syncthreads();

    if (t < NB && rank[t] > 0u) hbase[t] = atomicAdd(&gctr[t], rank[t]);
    __syncthreads();

    #pragma unroll
    for (int kk = 0; kk < 2; ++kk) {
        if (vk[kk]) {
            #define PUT(i) { \
                unsigned int b = pbr[kk * 4 + i] >> 16; \
                unsigned int slot = hbase[b] + (pbr[kk * 4 + i] & 0xFFFFu); \
                if (slot < MAXPB) payload[(size_t)b * MAXPB + slot] = pw[kk * 4 + i]; }
            PUT(0) PUT(1) PUT(2) PUT(3)
            #undef PUT
        }
    }
}

// Per bucket, 1024 threads: LDS degree histogram; write rsv = rsqrt(deg), g = rsv*f.
__global__ __launch_bounds__(1024) void k_bdeg_g(const unsigned int* __restrict__ gctr,
                                                 const unsigned int* __restrict__ payload,
                                                 const float* __restrict__ nf,
                                                 float* __restrict__ rsv, float* __restrict__ g) {
    __shared__ unsigned int hist[NPB];
    const int b = blockIdx.x, t = threadIdx.x;
    if (t < NPB) hist[t] = 0u;
    __syncthreads();
    const unsigned int cnt = min(gctr[b], (unsigned int)MAXPB);
    const unsigned int* pl = payload + (size_t)b * MAXPB;
    const uint4* pl4 = reinterpret_cast<const uint4*>(pl);
    const unsigned int nv = cnt >> 2;
    for (unsigned int k = t; k < nv; k += 1024) {
        uint4 p = pl4[k];
        atomicAdd(&hist[p.x & (NPB - 1)], 1u);
        atomicAdd(&hist[p.y & (NPB - 1)], 1u);
        atomicAdd(&hist[p.z & (NPB - 1)], 1u);
        atomicAdd(&hist[p.w & (NPB - 1)], 1u);
    }
    for (unsigned int k = (nv << 2) + t; k < cnt; k += 1024)
        atomicAdd(&hist[pl[k] & (NPB - 1)], 1u);
    __syncthreads();
    if (t < NPB) {
        int node = (b << BSH) + t;
        if (node < NN) {
            float df = 1.0f + (float)hist[t];
            float rs = rsqrtf(df);
            rsv[node] = rs;
            float2 f = *reinterpret_cast<const float2*>(&nf[2 * node]);
            float2 gv; gv.x = rs * f.x; gv.y = rs * f.y;
            *reinterpret_cast<float2*>(&g[2 * node]) = gv;
        }
    }
}

// Per bucket, 1024 threads: aggregate g[src] into x/y LDS planes, fold self-loop,
// GCN channel pass + relu; atomic S/T2; LAST block runs the FC tail in-place.
// NOTE: no __threadfence() — r11: device fence = per-block L2 invalidate storm
// (+100 µs). syncthreads' vmcnt drain + memory-side atomics publish S/T2.
__global__ __launch_bounds__(1024) void k_bagg_node(const unsigned int* __restrict__ gctr,
        const unsigned int* __restrict__ payload,
        const float* __restrict__ g, const float* __restrict__ rsv,
        const float* __restrict__ gcn_w, const float* __restrict__ gcn_b,
        float* __restrict__ S, float* __restrict__ T2, unsigned int* __restrict__ done,
        const float* __restrict__ zpart,
        const float* __restrict__ ln_w, const float* __restrict__ ln_b,
        const float* __restrict__ fc1_w, const float* __restrict__ fc1_b,
        const float* __restrict__ fc2_w, const float* __restrict__ fc2_b,
        float* __restrict__ out) {
    __shared__ union {
        struct { float agg[NPB * 2]; float shSf[HH]; float shw[16]; } ba;
        struct { float psum[8][HH]; float pooled[HH]; float z[HH];
                 float logits[AA]; float red[2]; } fin;
    } u;
    __shared__ int s_last;
    const int b = blockIdx.x, t = threadIdx.x;
    if (t < NPB * 2) u.ba.agg[t] = 0.f;
    if (t < HH) u.ba.shSf[t] = 0.f;
    __syncthreads();
    const unsigned int cnt = min(gctr[b], (unsigned int)MAXPB);
    const unsigned int* pl = payload + (size_t)b * MAXPB;
    const uint4* pl4 = reinterpret_cast<const uint4*>(pl);
    const unsigned int nv = cnt >> 2;
    for (unsigned int k = t; k < nv; k += 1024) {
        uint4 p = pl4[k];
        #define ACC(P) { \
            unsigned int s = (P) >> BSH, dl = (P) & (NPB - 1); \
            float2 gv = *reinterpret_cast<const float2*>(&g[2 * s]); \
            atomicAdd(&u.ba.agg[dl],       gv.x); \
            atomicAdd(&u.ba.agg[NPB + dl], gv.y); }
        ACC(p.x) ACC(p.y) ACC(p.z) ACC(p.w)
        #undef ACC
    }
    for (unsigned int k = (nv << 2) + t; k < cnt; k += 1024) {
        unsigned int p = pl[k];
        unsigned int s = p >> BSH, dl = p & (NPB - 1);
        float2 gv = *reinterpret_cast<const float2*>(&g[2 * s]);
        atomicAdd(&u.ba.agg[dl],       gv.x);
        atomicAdd(&u.ba.agg[NPB + dl], gv.y);
    }
    __syncthreads();

    const int nvalid = min(NPB, NN - (b << BSH));
    if (t < nvalid) {
        int node = (b << BSH) + t;
        float rs = rsv[node];
        float2 gv = *reinterpret_cast<const float2*>(&g[2 * node]);
        u.ba.agg[t]       = rs * (u.ba.agg[t]       + gv.x);
        u.ba.agg[NPB + t] = rs * (u.ba.agg[NPB + t] + gv.y);
    }
    __syncthreads();

    const int ch = t & (HH - 1), slot = t >> 7;
    {
        const float w0 = gcn_w[ch], w1 = gcn_w[HH + ch], bb = gcn_b[ch];
        float accS = 0.f, accT2 = 0.f;
        for (int j = slot; j < nvalid; j += 8) {
            float x = fmaf(u.ba.agg[j], w0, fmaf(u.ba.agg[NPB + j], w1, bb));
            float r = fmaxf(x, 0.f);
            accS  += r;
            accT2 += r * r;
        }
        atomicAdd(&u.ba.shSf[ch], accS);
        float v = accT2;
        for (int o = 32; o; o >>= 1) v += __shfl_down(v, o, 64);
        if ((t & 63) == 0) u.ba.shw[t >> 6] = v;
        __syncthreads();
        if (t < HH) atomicAdd(&S[t], u.ba.shSf[t]);
        if (t == 0) {
            float s2 = 0.f;
            #pragma unroll
            for (int w = 0; w < 16; ++w) s2 += u.ba.shw[w];
            atomicAdd(T2, s2);
        }
    }
    // ---- last-block election (S/T2 adds drained by syncthreads' vmcnt wait) ----
    __syncthreads();
    if (t == 0) {
        unsigned int old = atomicAdd(done, 1u);
        s_last = (old == NB - 1) ? 1 : 0;
    }
    __syncthreads();
    if (!s_last) return;

    // ---- tail (r8 k_final2 body), agent-scope atomic loads for S/T2 ----
    const int sl = t >> 7;
    if (t < HH) {
        float s = __hip_atomic_load(&S[t], __ATOMIC_RELAXED, __HIP_MEMORY_SCOPE_AGENT);
        u.fin.pooled[t] = s;
        float vv = s;
        for (int o = 32; o; o >>= 1) vv += __shfl_down(vv, o, 64);
        if ((t & 63) == 0) u.fin.red[t >> 6] = vv;
    }
    __syncthreads();
    const float T1 = u.fin.red[0] + u.fin.red[1];
    const float T2v = __hip_atomic_load(T2, __ATOMIC_RELAXED, __HIP_MEMORY_SCOPE_AGENT);
    const float cntf = (float)NN * (float)HH;
    const float mean = T1 / cntf;
    const float var  = T2v / cntf - mean * mean;
    const float denom = sqrtf(var) + LN_EPS;
    if (t < HH)
        u.fin.pooled[t] = ln_w[t] * (u.fin.pooled[t] - (float)NN * mean) / denom + (float)NN * ln_b[t];
    __syncthreads();

    float acc = 0.f;
    for (int k = sl * 16; k < sl * 16 + 16; ++k)
        acc = fmaf(u.fin.pooled[k], fc1_w[(size_t)k * HH + ch], acc);
    for (int w = sl * 8; w < sl * 8 + 8; ++w)
        acc += zpart[(size_t)w * HH + ch];
    u.fin.psum[sl][ch] = acc;
    __syncthreads();
    if (t < HH) {
        float a = fc1_b[t];
        #pragma unroll
        for (int k = 0; k < 8; ++k) a += u.fin.psum[k][t];
        u.fin.z[t] = fmaxf(a, 0.f);
    }
    __syncthreads();

    if (t < AA) {
        float l = fc2_b[t];
        for (int j = 0; j < HH; ++j)
            l = fmaf(u.fin.z[j], fc2_w[j * AA + t], l);
        u.fin.logits[t] = l;
    }
    __syncthreads();

    if (t == 0) {
        float m = u.fin.logits[0];
        for (int a = 1; a < AA; ++a) m = fmaxf(m, u.fin.logits[a]);
        float sum = 0.f;
        for (int a = 0; a < AA; ++a) sum += expf(u.fin.logits[a] - m);
        float lse = m + logf(sum);
        for (int a = 0; a < AA; ++a) out[a] = u.fin.logits[a] - lse;
    }
}

// ---------------- fallback path (round-2 known-good) ----------------

__global__ void k_initf(unsigned int* __restrict__ p, int n) {
    int i = blockIdx.x * blockDim.x + threadIdx.x;
    int stride = gridDim.x * blockDim.x;
    for (int j = i; j < n; j += stride) p[j] = 0u;
}

__global__ void k_deg1(const int* __restrict__ dst, int* __restrict__ deg, int e) {
    int i = blockIdx.x * blockDim.x + threadIdx.x;
    if (i < e) atomicAdd(&deg[dst[i]], 1);
}

__global__ void k_g1(const int* __restrict__ deg, const float* __restrict__ nf,
                     float* __restrict__ degf, float* __restrict__ g, int n) {
    int i = blockIdx.x * blockDim.x + threadIdx.x;
    if (i < n) {
        float df = (float)(1 + deg[i]);
        degf[i] = df;
        float rs = rsqrtf(df);
        float2 f = *reinterpret_cast<const float2*>(&nf[2 * i]);
        float2 gv; gv.x = rs * f.x; gv.y = rs * f.y;
        *reinterpret_cast<float2*>(&g[2 * i]) = gv;
    }
}

__global__ void k_edge1(const int* __restrict__ src, const int* __restrict__ dst,
                        const float* __restrict__ g, float* __restrict__ B, int e) {
    int i = blockIdx.x * blockDim.x + threadIdx.x;
    if (i < e) {
        int s = src[i], d = dst[i];
        float2 gv = *reinterpret_cast<const float2*>(&g[2 * s]);
        atomicAdd(&B[2 * d],     gv.x);
        atomicAdd(&B[2 * d + 1], gv.y);
    }
}

__global__ void k_node(const float* __restrict__ nf, const float* __restrict__ degf,
                       const float* __restrict__ B,
                       const float* __restrict__ gcn_w, const float* __restrict__ gcn_b,
                       float* __restrict__ S, float* __restrict__ T2, int n) {
    const int ch   = threadIdx.x & (HH - 1);
    const int slot = threadIdx.x >> 7;
    const float w0 = gcn_w[ch];
    const float w1 = gcn_w[HH + ch];
    const float b  = gcn_b[ch];
    float accS = 0.f, accT2 = 0.f;
    for (int i = blockIdx.x * 2 + slot; i < n; i += gridDim.x * 2) {
        float df   = degf[i];
        float invd = 1.0f / df;
        float rs   = rsqrtf(df);
        float2 bv = *reinterpret_cast<const float2*>(&B[2 * i]);
        float2 f  = *reinterpret_cast<const float2*>(&nf[2 * i]);
        float b0 = rs * bv.x + f.x * invd;
        float b1 = rs * bv.y + f.y * invd;
        float xv = fmaf(b0, w0, fmaf(b1, w1, b));
        float r  = fmaxf(xv, 0.f);
        accS  += r;
        accT2 += r * r;
    }
    __shared__ float shS[HH];
    if (slot == 1) shS[ch] = accS;
    __syncthreads();
    if (slot == 0) atomicAdd(&S[ch], accS + shS[ch]);
    float v = accT2;
    for (int o = 32; o; o >>= 1) v += __shfl_down(v, o, 64);
    __shared__ float shw[4];
    if ((threadIdx.x & 63) == 0) shw[threadIdx.x >> 6] = v;
    __syncthreads();
    if (threadIdx.x == 0) atomicAdd(T2, shw[0] + shw[1] + shw[2] + shw[3]);
}

__global__ void k_final(const float* __restrict__ S, const float* __restrict__ T2ptr,
                        const float* __restrict__ esn,
                        const float* __restrict__ ln_w, const float* __restrict__ ln_b,
                        const float* __restrict__ fc1_w, const float* __restrict__ fc1_b,
                        const float* __restrict__ fc2_w, const float* __restrict__ fc2_b,
                        float* __restrict__ out) {
    const int t = threadIdx.x;
    __shared__ float sh_pooled[HH];
    __shared__ float sh_z[HH];
    __shared__ float sh_logits[AA];
    __shared__ float shred[2];

    float s = S[t];
    float v = s;
    for (int o = 32; o; o >>= 1) v += __shfl_down(v, o, 64);
    if ((t & 63) == 0) shred[t >> 6] = v;
    __syncthreads();
    const float T1 = shred[0] + shred[1];
    const float T2 = *T2ptr;
    const float cnt = (float)NN * (float)HH;
    const float mean = T1 / cnt;
    const float var  = T2 / cnt - mean * mean;
    const float denom = sqrtf(var) + LN_EPS;
    sh_pooled[t] = ln_w[t] * (s - (float)NN * mean) / denom + (float)NN * ln_b[t];
    __syncthreads();

    float acc = fc1_b[t];
    for (int k = 0; k < HH; ++k)
        acc = fmaf(sh_pooled[k], fc1_w[k * HH + t], acc);
    for (int k = 0; k < RR; ++k)
        acc = fmaf(esn[k], fc1_w[(HH + k) * HH + t], acc);
    sh_z[t] = fmaxf(acc, 0.f);
    __syncthreads();

    if (t < AA) {
        float l = fc2_b[t];
        for (int j = 0; j < HH; ++j)
            l = fmaf(sh_z[j], fc2_w[j * AA + t], l);
        sh_logits[t] = l;
    }
    __syncthreads();

    if (t == 0) {
        float m = sh_logits[0];
        for (int a = 1; a < AA; ++a) m = fmaxf(m, sh_logits[a]);
        float sum = 0.f;
        for (int a = 0; a < AA; ++a) sum += expf(sh_logits[a] - m);
        float lse = m + logf(sum);
        for (int a = 0; a < AA; ++a) out[a] = sh_logits[a] - lse;
    }
}

extern "C" void kernel_launch(void* const* d_in, const int* in_sizes, int n_in,
                              void* d_out, int out_size, void* d_ws, size_t ws_size,
                              hipStream_t stream) {
    const float* nf     = (const float*)d_in[0];
    const int*   ei     = (const int*)d_in[1];
    const float* esn    = (const float*)d_in[2];
    const float* gcn_w  = (const float*)d_in[3];
    const float* gcn_b  = (const float*)d_in[4];
    const float* ln_w   = (const float*)d_in[5];
    const float* ln_b   = (const float*)d_in[6];
    const float* fc1_w  = (const float*)d_in[7];
    const float* fc1_b  = (const float*)d_in[8];
    const float* fc2_w  = (const float*)d_in[9];
    const float* fc2_b  = (const float*)d_in[10];
    float* out = (float*)d_out;
    float* ws  = (float*)d_ws;

    // Layout (word offsets) — r12-proven:
    //   gctr:0(512) | S:512(128) | T2:640 | done:641 | zpart:644(64*128) | payload | rsv | g
    const size_t OFF_S       = 512;
    const size_t OFF_T2      = OFF_S + HH;                          // 640
    const size_t OFF_DONE    = OFF_T2 + 1;                          // 641
    const size_t OFF_ZPART   = 644;
    const size_t OFF_PAYLOAD = OFF_ZPART + (size_t)NZW * HH;        // 8836 (mult of 4)
    const size_t OFF_RSV     = OFF_PAYLOAD + (size_t)NB * MAXPB;
    const size_t OFF_G       = OFF_RSV + NN;                        // even -> float2 ok
    const size_t NEED_BKT    = (OFF_G + 2 * (size_t)NN) * 4;

    if (ws_size >= NEED_BKT) {
        unsigned int* gctr    = (unsigned int*)ws;
        float*        S       = ws + OFF_S;
        float*        T2      = ws + OFF_T2;
        unsigned int* done    = (unsigned int*)ws + OFF_DONE;
        float*        zpart   = ws + OFF_ZPART;
        unsigned int* payload = (unsigned int*)ws + OFF_PAYLOAD;
        float*        rsv     = ws + OFF_RSV;
        float*        g       = ws + OFF_G;

        hipLaunchKernelGGL(k_init_esn,  dim3(NZW + 1), dim3(256),  0, stream, (unsigned int*)ws, esn, fc1_w, zpart);
        hipLaunchKernelGGL(k_scatter,   dim3(NWG_SC),  dim3(SCT),  0, stream, ei, ei + EE, gctr, payload);
        hipLaunchKernelGGL(k_bdeg_g,    dim3(NB),      dim3(1024), 0, stream, gctr, payload, nf, rsv, g);
        hipLaunchKernelGGL(k_bagg_node, dim3(NB),      dim3(1024), 0, stream,
                           gctr, payload, g, rsv, gcn_w, gcn_b, S, T2, done, zpart,
                           ln_w, ln_b, fc1_w, fc1_b, fc2_w, fc2_b, out);
    } else {
        // Fallback: known-good atomic path.
        int*   deg  = (int*)ws;
        float* B    = ws + NN;
        float* S    = ws + 3 * (size_t)NN;
        float* T2   = ws + 3 * (size_t)NN + 128;
        float* degf = ws + 3 * (size_t)NN + 130;
        float* g    = ws + 4 * (size_t)NN + 130;
        const int eb = (EE + 255) / 256;
        const int nb = (NN + 255) / 256;
        hipLaunchKernelGGL(k_initf, dim3(2048), dim3(256), 0, stream, (unsigned int*)ws, 3 * NN + 129);
        hipLaunchKernelGGL(k_deg1,  dim3(eb),   dim3(256), 0, stream, ei + EE, deg, EE);
        hipLaunchKernelGGL(k_g1,    dim3(nb),   dim3(256), 0, stream, deg, nf, degf, g, NN);
        hipLaunchKernelGGL(k_edge1, dim3(eb),   dim3(256), 0, stream, ei, ei + EE, g, B, EE);
        hipLaunchKernelGGL(k_node,  dim3(512),  dim3(256), 0, stream, nf, degf, B, gcn_w, gcn_b, S, T2, NN);
        hipLaunchKernelGGL(k_final, dim3(1),    dim3(128), 0, stream,
                           S, T2, esn, ln_w, ln_b, fc1_w, fc1_b, fc2_w, fc2_b, out);
    }
}